// Round 20
// baseline (203.213 us; speedup 1.0000x reference)
//
#include <hip/hip_runtime.h>

typedef unsigned short u16;
typedef unsigned int u32;
typedef __bf16 bf16x8 __attribute__((ext_vector_type(8)));
typedef float f32x4 __attribute__((ext_vector_type(4)));
typedef float f32x16 __attribute__((ext_vector_type(16)));
typedef unsigned short u16x8 __attribute__((ext_vector_type(8)));
typedef unsigned short u16x4 __attribute__((ext_vector_type(4)));

#define LOG2E 1.44269504088896f

__device__ __forceinline__ float fast_exp2(float x) {
#if __has_builtin(__builtin_amdgcn_exp2f)
  return __builtin_amdgcn_exp2f(x);
#else
  return exp2f(x);
#endif
}

// HW bf16 convert (compiler emits v_cvt_pk_bf16_f32 pairs)
__device__ __forceinline__ u16 f2bf(float x) {
  union { __bf16 b; u16 u; } c;
  c.b = (__bf16)x;
  return c.u;
}

// packed f32x2 -> bf16x2 in one instruction (no builtin on gfx950; T12)
__device__ __forceinline__ u32 cvtpk_bf16(float lo_, float hi_) {
  u32 r;
  asm("v_cvt_pk_bf16_f32 %0, %1, %2" : "=v"(r) : "v"(lo_), "v"(hi_));
  return r;
}

// v_permlane32_swap_b32: a[l>=32] <-> b[l<32].
__device__ __forceinline__ void permswap32(u32& a, u32& b) {
  asm volatile("v_permlane32_swap_b32 %0, %1" : "+v"(a), "+v"(b));
}

__device__ __forceinline__ void gload_lds16(const void* g, void* l) {
  __builtin_amdgcn_global_load_lds(
      (__attribute__((address_space(1))) void*)(g),
      (__attribute__((address_space(3))) void*)(l), 16, 0, 0);
}

// XOR bank swizzle for [rows][64 u16] LDS tiles, 16B-chunk granularity
// (attn tiles, row stride 128B).
__device__ __forceinline__ int swz_off(int row, int col) {
  return row * 64 + ((((col >> 3) ^ (row ^ (row >> 3))) & 7) << 3) + (col & 7);
}

// ---------------- all 4 weights: W (K x N) -> W^T (N x K) bf16, one dispatch --
__global__ __launch_bounds__(256) void transpose_cvt4(
    const float* __restrict__ Wq, const float* __restrict__ Wk,
    const float* __restrict__ Wv, const float* __restrict__ Wo,
    u16* __restrict__ Wqt, u16* __restrict__ Wkt,
    u16* __restrict__ Wvt, u16* __restrict__ Wot) {
  const int E = 1024;
  const float* W = blockIdx.z == 0 ? Wq : blockIdx.z == 1 ? Wk
                   : blockIdx.z == 2 ? Wv : Wo;
  u16* Wt = blockIdx.z == 0 ? Wqt : blockIdx.z == 1 ? Wkt
            : blockIdx.z == 2 ? Wvt : Wot;
  __shared__ float tile[32][33];
  int tx = threadIdx.x & 31, ty = threadIdx.x >> 5;  // 32 x 8
  int bx = blockIdx.x * 32, by = blockIdx.y * 32;
  #pragma unroll
  for (int i = 0; i < 32; i += 8)
    tile[ty + i][tx] = W[(size_t)(by + ty + i) * E + bx + tx];
  __syncthreads();
  #pragma unroll
  for (int i = 0; i < 32; i += 8)
    Wt[(size_t)(bx + ty + i) * E + by + tx] = f2bf(tile[tx][ty + i]);
}

// ---------------- fused Q/K/V projection, BK=32, dbuf + counted vmcnt (T4) --
// Raw s_barrier (no vmcnt drain) + double-buffered LDS + s_waitcnt vmcnt(6):
// the 6 prefetch gloads for tile t+1 stay in flight ACROSS the barrier while
// tile t computes. Schedule: barrier -> issue(t+1)->buf[p^1] -> vmcnt(6) ->
// sched_barrier -> compute buf[p]. Safety: issue into buf[p^1] happens after
// barrier(t); its readers (compute t-1) finished before barrier(t).
__global__ __launch_bounds__(256) void proj_qkv(
    const float* __restrict__ Xq, const float* __restrict__ Xk,
    const float* __restrict__ Xv,
    const u16* __restrict__ Wqt, const u16* __restrict__ Wkt,
    const u16* __restrict__ Wvt,
    const float* __restrict__ bq, const float* __restrict__ bk,
    const float* __restrict__ bv,
    u16* __restrict__ Qp, u16* __restrict__ Kp, u16* __restrict__ Vp,
    float qscale)
{
  constexpr int K = 1024, N = 1024, NT = K / 32;
  // bid <-> (xcd, seq) <-> (panel, col): bijective (r19 mapping)
  const int bid = blockIdx.x;          // 0..1535
  const int xcd = bid & 7;
  const int seq = bid >> 3;            // 0..191
  const int pan = xcd * 24 + (seq >> 3);
  const int xcol = seq & 7;
  const int z = pan / 64;
  const int y = pan % 64;

  const float* A; const u16* Bt; const float* bias; u16* C; float oscale;
  if (z == 0)      { A = Xq; Bt = Wqt; bias = bq; C = Qp; oscale = qscale; }
  else if (z == 1) { A = Xk; Bt = Wkt; bias = bk; C = Kp; oscale = 1.f; }
  else             { A = Xv; Bt = Wvt; bias = bv; C = Vp; oscale = 1.f; }

  __shared__ float As32[2][128 * 32];  // fp32 A tile, XOR-swz source
  __shared__ u16 Bs[2][128 * 32];      // bf16 B tile, XOR-swz source
  const int tid = threadIdx.x;
  const int w = tid >> 6;
  const int lane = tid & 63;
  const int lo = lane & 15, hi = lane >> 4;
  const int brow = y * 128;
  const int bcol = xcol * 128;
  const int wr = (w >> 1) * 64;
  const int wc = (w & 1) * 64;

  f32x4 acc[4][4] = {};

  // issue the 6 gloads (2 B + 4 A) for k-step k0 into buffer b
  auto issue = [&](int k0, int b) {
    #pragma unroll
    for (int i = 0; i < 2; i++) {
      int g = i * 256 + tid;
      int row = g >> 2;
      int lc = (g & 3) ^ ((row >> 1) & 3);
      gload_lds16(Bt + (size_t)(bcol + row) * K + k0 + lc * 8,
                  (void*)(&Bs[b][0] + (size_t)g * 8));
    }
    #pragma unroll
    for (int i = 0; i < 4; i++) {
      int g = i * 256 + tid;
      int row = g >> 3;
      int lc = (g & 7) ^ (row & 7);
      gload_lds16(A + (size_t)(brow + row) * K + k0 + lc * 4,
                  (void*)(&As32[b][0] + (size_t)g * 4));
    }
  };

  issue(0, 0);
  for (int t = 0; t < NT; t++) {
    const int p = t & 1;
    __builtin_amdgcn_s_barrier();        // raw barrier: no vmcnt drain
    __builtin_amdgcn_sched_barrier(0);
    if (t + 1 < NT) {
      issue((t + 1) * 32, p ^ 1);
      asm volatile("s_waitcnt vmcnt(6)" ::: "memory");  // buf[p]'s 6 done
    } else {
      asm volatile("s_waitcnt vmcnt(0)" ::: "memory");
    }
    __builtin_amdgcn_sched_barrier(0);

    const float* as = &As32[p][0];
    const u16* bs = &Bs[p][0];
    __builtin_amdgcn_s_setprio(1);
    bf16x8 af[4], bfr[4];
    #pragma unroll
    for (int mi = 0; mi < 4; mi++) {
      int row = wr + mi * 16 + lo;
      int s_ = row & 7;
      int c0 = hi * 2;
      f32x4 fa = *(const f32x4*)(as + row * 32 + ((c0 ^ s_) << 2));
      f32x4 fb = *(const f32x4*)(as + row * 32 + (((c0 + 1) ^ s_) << 2));
      union { u32 d[4]; bf16x8 v; } ua;
      ua.d[0] = cvtpk_bf16(fa[0], fa[1]);
      ua.d[1] = cvtpk_bf16(fa[2], fa[3]);
      ua.d[2] = cvtpk_bf16(fb[0], fb[1]);
      ua.d[3] = cvtpk_bf16(fb[2], fb[3]);
      af[mi] = ua.v;
    }
    #pragma unroll
    for (int ni = 0; ni < 4; ni++) {
      int row = wc + ni * 16 + lo;
      int ch = hi ^ ((row >> 1) & 3);
      bfr[ni] = *(const bf16x8*)(bs + row * 32 + ch * 8);
    }
    #pragma unroll
    for (int mi = 0; mi < 4; mi++)
      #pragma unroll
      for (int ni = 0; ni < 4; ni++)
        acc[mi][ni] = __builtin_amdgcn_mfma_f32_16x16x32_bf16(
            af[mi], bfr[ni], acc[mi][ni], 0, 0, 0);
    __builtin_amdgcn_s_setprio(0);
  }

  #pragma unroll
  for (int mi = 0; mi < 4; mi++)
    #pragma unroll
    for (int ni = 0; ni < 4; ni++) {
      int row = brow + wr + mi * 16 + hi * 4;
      int col = bcol + wc + ni * 16 + lo;
      float bv = bias[col];
      #pragma unroll
      for (int r = 0; r < 4; r++) {
        float v = (acc[mi][ni][r] + bv) * oscale;
        C[(size_t)(row + r) * N + col] = f2bf(v);
      }
    }
}

// ---------------- output projection, BK=32, panel-grouped XCD swizzle -------
__global__ __launch_bounds__(256) void gemm_out(
    const u16* __restrict__ A, const u16* __restrict__ Bt,
    const float* __restrict__ bias, float* __restrict__ C)
{
  constexpr int K = 1024, N = 1024;
  const int bid = blockIdx.x;          // 0..511
  const int xcd = bid & 7;
  const int seq = bid >> 3;            // 0..63
  const int pan = xcd * 8 + (seq >> 3);   // 0..63 row panel
  const int xcol = seq & 7;
  __shared__ u16 As[128 * 32];
  __shared__ u16 Bs[128 * 32];
  const int tid = threadIdx.x;
  const int w = tid >> 6;
  const int lane = tid & 63;
  const int lo = lane & 15, hi = lane >> 4;
  const int brow = pan * 128;
  const int bcol = xcol * 128;
  const int wr = (w >> 1) * 64;
  const int wc = (w & 1) * 64;

  f32x4 acc[4][4] = {};

  for (int k0 = 0; k0 < K; k0 += 32) {
    __syncthreads();
    #pragma unroll
    for (int i = 0; i < 2; i++) {
      int g = i * 256 + tid;
      int row = g >> 2;
      int lc = (g & 3) ^ ((row >> 1) & 3);
      gload_lds16(A + (size_t)(brow + row) * K + k0 + lc * 8,
                  (void*)(As + (size_t)g * 8));
      gload_lds16(Bt + (size_t)(bcol + row) * K + k0 + lc * 8,
                  (void*)(Bs + (size_t)g * 8));
    }
    __syncthreads();
    __builtin_amdgcn_s_setprio(1);
    bf16x8 af[4], bfr[4];
    #pragma unroll
    for (int mi = 0; mi < 4; mi++) {
      int row = wr + mi * 16 + lo;
      int ch = hi ^ ((row >> 1) & 3);
      af[mi] = *(const bf16x8*)(As + row * 32 + ch * 8);
    }
    #pragma unroll
    for (int ni = 0; ni < 4; ni++) {
      int row = wc + ni * 16 + lo;
      int ch = hi ^ ((row >> 1) & 3);
      bfr[ni] = *(const bf16x8*)(Bs + row * 32 + ch * 8);
    }
    #pragma unroll
    for (int mi = 0; mi < 4; mi++)
      #pragma unroll
      for (int ni = 0; ni < 4; ni++)
        acc[mi][ni] = __builtin_amdgcn_mfma_f32_16x16x32_bf16(
            af[mi], bfr[ni], acc[mi][ni], 0, 0, 0);
    __builtin_amdgcn_s_setprio(0);
  }

  #pragma unroll
  for (int mi = 0; mi < 4; mi++)
    #pragma unroll
    for (int ni = 0; ni < 4; ni++) {
      int row = brow + wr + mi * 16 + hi * 4;
      int col = bcol + wc + ni * 16 + lo;
      float bv = bias[col];
      #pragma unroll
      for (int r = 0; r < 4; r++)
        C[(size_t)(row + r) * N + col] = acc[mi][ni][r] + bv;
    }
}

// ---------------- flash attention (r17-proven: per-sb interleave) ----------
__global__ __launch_bounds__(256) void attn_kernel(
    const u16* __restrict__ Qp, const u16* __restrict__ Kp,
    const u16* __restrict__ Vp, u16* __restrict__ O)
{
  constexpr int Bb = 4, E = 1024, Nn = 2048;
  constexpr int NT = Nn / 64;
  __shared__ u16 Ks[2][64 * 64];    // K tile [n][d], swizzled
  __shared__ u16 Vt[2][64 * 64];    // V^T tile [d][n], swizzled

  const int tid = threadIdx.x;
  const int lane = tid & 63;
  const int w = tid >> 6;
  const int l31 = lane & 31;        // this lane's q-row (col of S^T)
  const int hi5 = lane >> 5;        // 0/1: half selector

  // XCD-grouping swizzle: blocks sharing (b,h) -> same XCD L2
  const int wg = blockIdx.x;
  const int swz = (wg & 7) * 128 + (wg >> 3);
  const int b_ = swz >> 8;
  const int h = (swz >> 4) & 15;
  const int mbase = (swz & 15) * 128 + w * 32;
  const int m = mbase + l31;

  // Q B-frags (pre-scaled by 1/sqrt(d)*log2e)
  bf16x8 q[4];
  {
    const u16* qrow = Qp + (size_t)(m * Bb + b_) * E + h * 64;
    #pragma unroll
    for (int kb = 0; kb < 4; kb++)
      q[kb] = *(const bf16x8*)(qrow + kb * 16 + hi5 * 8);
  }

  f32x16 oacc[2] = {};              // O^T: col=m, row=d (2 d-subtiles)
  float lrun = 0.f;                 // per-lane PARTIAL (own 32 n of row m)

  // staging assignments + strength-reduced pointers
  const int nrK = tid >> 3;            // + i*32
  const int q8K = (tid & 7) * 8;
  const int dq = (tid & 15) * 4;       // V: 4x4 block at (nq.., dq..)
  const int nq = (tid >> 4) * 4;
  const size_t rstride = (size_t)Bb * E;          // one n-row
  const size_t KSTEP = 64 * rstride;              // one KV tile
  const u16* kpt = Kp + (size_t)nrK * rstride + (size_t)b_ * E + h * 64 + q8K;
  const u16* vpt = Vp + (size_t)nq * rstride + (size_t)b_ * E + h * 64 + dq;

  // prefetch tile 0
  u16x8 kreg[2];
  u16x4 vreg[4];
  kreg[0] = *(const u16x8*)(kpt);
  kreg[1] = *(const u16x8*)(kpt + 32 * rstride);
  #pragma unroll
  for (int j = 0; j < 4; j++)
    vreg[j] = *(const u16x4*)(vpt + j * rstride);
  kpt += KSTEP; vpt += KSTEP;

  int it = 0;
  for (int t = 0; t < NT; t++, it ^= 1) {
    // stage regs -> LDS buf[it]
    #pragma unroll
    for (int i = 0; i < 2; i++)
      *(u16x8*)(&Ks[it][swz_off(i * 32 + nrK, q8K)]) = kreg[i];
    #pragma unroll
    for (int jw = 0; jw < 4; jw++) {
      u16x4 colv;
      #pragma unroll
      for (int j = 0; j < 4; j++) colv[j] = vreg[j][jw];
      *(u16x4*)(&Vt[it][swz_off(dq + jw, nq)]) = colv;
    }
    __syncthreads();
    // issue next tile's global loads; they retire under compute
    if (t < NT - 1) {
      kreg[0] = *(const u16x8*)(kpt);
      kreg[1] = *(const u16x8*)(kpt + 32 * rstride);
      #pragma unroll
      for (int j = 0; j < 4; j++)
        vreg[j] = *(const u16x4*)(vpt + j * rstride);
      kpt += KSTEP; vpt += KSTEP;
    }
    const u16* ksp = &Ks[it][0];
    const u16* vtp = &Vt[it][0];

    // S^T = K Q^T (log2 domain), 32x32x16
    f32x16 st[2];
    __builtin_amdgcn_s_setprio(1);
    #pragma unroll
    for (int sb = 0; sb < 2; sb++) {
      f32x16 tacc = {};
      #pragma unroll
      for (int kb = 0; kb < 4; kb++) {
        bf16x8 kf = *(const bf16x8*)(ksp + swz_off(sb * 32 + l31, kb * 16 + hi5 * 8));
        tacc = __builtin_amdgcn_mfma_f32_32x32x16_bf16(kf, q[kb], tacc, 0, 0, 0);
      }
      st[sb] = tacc;
    }
    __builtin_amdgcn_s_setprio(0);

    // per-sb: exp2/pack(sb) -> pb(sb) -> PV(sb) ; exp2(sb1) overlaps PV(sb0)
    #pragma unroll
    for (int sb = 0; sb < 2; sb++) {
      u32 pks[8];
      float ra = 0.f, rb = 0.f, rc = 0.f, rd = 0.f;
      #pragma unroll
      for (int j = 0; j < 8; j++) {
        float p0 = fast_exp2(st[sb][2 * j]);
        float p1 = fast_exp2(st[sb][2 * j + 1]);
        if (j & 1) { ra += p0; rb += p1; } else { rc += p0; rd += p1; }
        pks[j] = cvtpk_bf16(p0, p1);
      }
      lrun += (ra + rb) + (rc + rd);

      bf16x8 pb[2];
      #pragma unroll
      for (int c = 0; c < 2; c++) {
        u32 a0 = pks[4 * c + 0], b0 = pks[4 * c + 2];
        u32 a1 = pks[4 * c + 1], b1 = pks[4 * c + 3];
        permswap32(a0, b0);
        permswap32(a1, b1);
        union { u32 d[4]; bf16x8 v; } u;
        u.d[0] = a0; u.d[1] = a1; u.d[2] = b0; u.d[3] = b1;
        pb[c] = u.v;
      }

      __builtin_amdgcn_s_setprio(1);
      #pragma unroll
      for (int dsb = 0; dsb < 2; dsb++) {
        #pragma unroll
        for (int c = 0; c < 2; c++) {
          int kb = sb * 2 + c;
          bf16x8 vf = *(const bf16x8*)(vtp + swz_off(dsb * 32 + l31, kb * 16 + hi5 * 8));
          oacc[dsb] = __builtin_amdgcn_mfma_f32_32x32x16_bf16(vf, pb[c], oacc[dsb], 0, 0, 0);
        }
      }
      __builtin_amdgcn_s_setprio(0);
    }
  }

  // epilogue: combine lrun across the lane pair (once), divide, store
  float l = lrun + __shfl_xor(lrun, 32);
  float inv = 1.f / l;
  u16* orow = O + (size_t)(m * Bb + b_) * E + h * 64;
  #pragma unroll
  for (int dsb = 0; dsb < 2; dsb++) {
    #pragma unroll
    for (int qd = 0; qd < 4; qd++) {
      u16x4 o;
      #pragma unroll
      for (int t = 0; t < 4; t++) o[t] = f2bf(oacc[dsb][qd * 4 + t] * inv);
      *(u16x4*)(orow + dsb * 32 + qd * 8 + hi5 * 4) = o;
    }
  }
}

extern "C" void kernel_launch(void* const* d_in, const int* in_sizes, int n_in,
                              void* d_out, int out_size, void* d_ws, size_t ws_size,
                              hipStream_t stream) {
  const float* query = (const float*)d_in[0];
  const float* key   = (const float*)d_in[1];
  const float* value = (const float*)d_in[2];
  const float* Wq = (const float*)d_in[3];
  const float* bq = (const float*)d_in[4];
  const float* Wk = (const float*)d_in[5];
  const float* bk = (const float*)d_in[6];
  const float* Wv = (const float*)d_in[7];
  const float* bv = (const float*)d_in[8];
  const float* Wo = (const float*)d_in[9];
  const float* bo = (const float*)d_in[10];
  float* out = (float*)d_out;

  const float QSCALE = 0.125f * LOG2E;  // 1/sqrt(64) * log2(e)

  const size_t XE = (size_t)2048 * 4 * 1024;  // M*B*E
  const size_t WE = (size_t)1024 * 1024;
  u16* ws  = (u16*)d_ws;
  u16* Qp  = ws;
  u16* Kp  = Qp + XE;
  u16* Vp  = Kp + XE;
  u16* Ob  = Vp + XE;       // attention output (bf16)
  u16* Wqt = Ob + XE;
  u16* Wkt = Wqt + WE;
  u16* Wvt = Wkt + WE;
  u16* Wot = Wvt + WE;

  dim3 blk(256);
  transpose_cvt4<<<dim3(32, 32, 4), blk, 0, stream>>>(
      Wq, Wk, Wv, Wo, Wqt, Wkt, Wvt, Wot);

  proj_qkv<<<1536, blk, 0, stream>>>(
      query, key, value, Wqt, Wkt, Wvt, bq, bk, bv, Qp, Kp, Vp, QSCALE);

  attn_kernel<<<1024, blk, 0, stream>>>(Qp, Kp, Vp, Ob);

  gemm_out<<<512, blk, 0, stream>>>(Ob, Wot, bo, out);
}

// Round 21
// 199.171 us; speedup vs baseline: 1.0203x; 1.0203x over previous
//
#include <hip/hip_runtime.h>

typedef unsigned short u16;
typedef unsigned int u32;
typedef __bf16 bf16x8 __attribute__((ext_vector_type(8)));
typedef float f32x4 __attribute__((ext_vector_type(4)));
typedef float f32x16 __attribute__((ext_vector_type(16)));
typedef unsigned short u16x8 __attribute__((ext_vector_type(8)));
typedef unsigned short u16x4 __attribute__((ext_vector_type(4)));

#define LOG2E 1.44269504088896f

__device__ __forceinline__ float fast_exp2(float x) {
#if __has_builtin(__builtin_amdgcn_exp2f)
  return __builtin_amdgcn_exp2f(x);
#else
  return exp2f(x);
#endif
}

// HW bf16 convert (compiler emits v_cvt_pk_bf16_f32 pairs)
__device__ __forceinline__ u16 f2bf(float x) {
  union { __bf16 b; u16 u; } c;
  c.b = (__bf16)x;
  return c.u;
}

// packed f32x2 -> bf16x2 in one instruction (no builtin on gfx950; T12)
__device__ __forceinline__ u32 cvtpk_bf16(float lo_, float hi_) {
  u32 r;
  asm("v_cvt_pk_bf16_f32 %0, %1, %2" : "=v"(r) : "v"(lo_), "v"(hi_));
  return r;
}

// v_permlane32_swap_b32: a[l>=32] <-> b[l<32].
__device__ __forceinline__ void permswap32(u32& a, u32& b) {
  asm volatile("v_permlane32_swap_b32 %0, %1" : "+v"(a), "+v"(b));
}

__device__ __forceinline__ void gload_lds16(const void* g, void* l) {
  __builtin_amdgcn_global_load_lds(
      (__attribute__((address_space(1))) void*)(g),
      (__attribute__((address_space(3))) void*)(l), 16, 0, 0);
}

// XOR bank swizzle for [rows][64 u16] LDS tiles, 16B-chunk granularity
// (attn tiles, row stride 128B).
__device__ __forceinline__ int swz_off(int row, int col) {
  return row * 64 + ((((col >> 3) ^ (row ^ (row >> 3))) & 7) << 3) + (col & 7);
}

// ---------------- all 4 weights: W (K x N) -> W^T (N x K) bf16, one dispatch --
__global__ __launch_bounds__(256) void transpose_cvt4(
    const float* __restrict__ Wq, const float* __restrict__ Wk,
    const float* __restrict__ Wv, const float* __restrict__ Wo,
    u16* __restrict__ Wqt, u16* __restrict__ Wkt,
    u16* __restrict__ Wvt, u16* __restrict__ Wot) {
  const int E = 1024;
  const float* W = blockIdx.z == 0 ? Wq : blockIdx.z == 1 ? Wk
                   : blockIdx.z == 2 ? Wv : Wo;
  u16* Wt = blockIdx.z == 0 ? Wqt : blockIdx.z == 1 ? Wkt
            : blockIdx.z == 2 ? Wvt : Wot;
  __shared__ float tile[32][33];
  int tx = threadIdx.x & 31, ty = threadIdx.x >> 5;  // 32 x 8
  int bx = blockIdx.x * 32, by = blockIdx.y * 32;
  #pragma unroll
  for (int i = 0; i < 32; i += 8)
    tile[ty + i][tx] = W[(size_t)(by + ty + i) * E + bx + tx];
  __syncthreads();
  #pragma unroll
  for (int i = 0; i < 32; i += 8)
    Wt[(size_t)(bx + ty + i) * E + by + tx] = f2bf(tile[tx][ty + i]);
}

// ---------------- fused Q/K/V projection, BK=32, panel-grouped XCD swizzle --
// Session-best variant (r19, 198.9 us): fully-async staging, single-buffered
// 24 KB LDS, A staged raw fp32 (pre-swizzled source), cvt at fragment-read.
__global__ __launch_bounds__(256) void proj_qkv(
    const float* __restrict__ Xq, const float* __restrict__ Xk,
    const float* __restrict__ Xv,
    const u16* __restrict__ Wqt, const u16* __restrict__ Wkt,
    const u16* __restrict__ Wvt,
    const float* __restrict__ bq, const float* __restrict__ bk,
    const float* __restrict__ bv,
    u16* __restrict__ Qp, u16* __restrict__ Kp, u16* __restrict__ Vp,
    float qscale)
{
  constexpr int K = 1024, N = 1024;
  // bid <-> (xcd, seq) <-> (panel, col): bijective
  const int bid = blockIdx.x;          // 0..1535
  const int xcd = bid & 7;
  const int seq = bid >> 3;            // 0..191
  const int pan = xcd * 24 + (seq >> 3);  // 0..191 (z,y panel)
  const int xcol = seq & 7;            // col tile
  const int z = pan / 64;
  const int y = pan % 64;

  const float* A; const u16* Bt; const float* bias; u16* C; float oscale;
  if (z == 0)      { A = Xq; Bt = Wqt; bias = bq; C = Qp; oscale = qscale; }
  else if (z == 1) { A = Xk; Bt = Wkt; bias = bk; C = Kp; oscale = 1.f; }
  else             { A = Xv; Bt = Wvt; bias = bv; C = Vp; oscale = 1.f; }

  __shared__ float As32[128 * 32];   // fp32 A tile, 8 16B-chunks/row, XOR swz
  __shared__ u16 Bs[128 * 32];       // bf16 B tile, 4 16B-chunks/row, XOR swz
  const int tid = threadIdx.x;
  const int w = tid >> 6;
  const int lane = tid & 63;
  const int lo = lane & 15, hi = lane >> 4;
  const int brow = y * 128;
  const int bcol = xcol * 128;
  const int wr = (w >> 1) * 64;
  const int wc = (w & 1) * 64;

  f32x4 acc[4][4] = {};

  for (int k0 = 0; k0 < K; k0 += 32) {
    __syncthreads();
    // B(t): 2 gload_lds (linear dest; source chunk pre-swizzled)
    #pragma unroll
    for (int i = 0; i < 2; i++) {
      int g = i * 256 + tid;
      int row = g >> 2;
      int lc = (g & 3) ^ ((row >> 1) & 3);
      gload_lds16(Bt + (size_t)(bcol + row) * K + k0 + lc * 8,
                  (void*)(Bs + (size_t)g * 8));
    }
    // A(t): 4 gload_lds fp32 (linear dest; source pre-swizzled)
    #pragma unroll
    for (int i = 0; i < 4; i++) {
      int g = i * 256 + tid;
      int row = g >> 3;
      int lc = (g & 7) ^ (row & 7);
      gload_lds16(A + (size_t)(brow + row) * K + k0 + lc * 4,
                  (void*)(As32 + (size_t)g * 4));
    }
    __syncthreads();   // drains all gloads

    __builtin_amdgcn_s_setprio(1);
    bf16x8 af[4], bfr[4];
    #pragma unroll
    for (int mi = 0; mi < 4; mi++) {
      int row = wr + mi * 16 + lo;
      int s_ = row & 7;
      int c0 = hi * 2;
      f32x4 fa = *(const f32x4*)(As32 + row * 32 + ((c0 ^ s_) << 2));
      f32x4 fb = *(const f32x4*)(As32 + row * 32 + (((c0 + 1) ^ s_) << 2));
      union { u32 d[4]; bf16x8 v; } ua;
      ua.d[0] = cvtpk_bf16(fa[0], fa[1]);
      ua.d[1] = cvtpk_bf16(fa[2], fa[3]);
      ua.d[2] = cvtpk_bf16(fb[0], fb[1]);
      ua.d[3] = cvtpk_bf16(fb[2], fb[3]);
      af[mi] = ua.v;
    }
    #pragma unroll
    for (int ni = 0; ni < 4; ni++) {
      int row = wc + ni * 16 + lo;
      int ch = hi ^ ((row >> 1) & 3);
      bfr[ni] = *(const bf16x8*)(Bs + row * 32 + ch * 8);
    }
    #pragma unroll
    for (int mi = 0; mi < 4; mi++)
      #pragma unroll
      for (int ni = 0; ni < 4; ni++)
        acc[mi][ni] = __builtin_amdgcn_mfma_f32_16x16x32_bf16(
            af[mi], bfr[ni], acc[mi][ni], 0, 0, 0);
    __builtin_amdgcn_s_setprio(0);
  }

  #pragma unroll
  for (int mi = 0; mi < 4; mi++)
    #pragma unroll
    for (int ni = 0; ni < 4; ni++) {
      int row = brow + wr + mi * 16 + hi * 4;
      int col = bcol + wc + ni * 16 + lo;
      float bv = bias[col];
      #pragma unroll
      for (int r = 0; r < 4; r++) {
        float v = (acc[mi][ni][r] + bv) * oscale;
        C[(size_t)(row + r) * N + col] = f2bf(v);
      }
    }
}

// ---------------- output projection, BK=32, panel-grouped XCD swizzle -------
__global__ __launch_bounds__(256) void gemm_out(
    const u16* __restrict__ A, const u16* __restrict__ Bt,
    const float* __restrict__ bias, float* __restrict__ C)
{
  constexpr int K = 1024, N = 1024;
  const int bid = blockIdx.x;          // 0..511
  const int xcd = bid & 7;
  const int seq = bid >> 3;            // 0..63
  const int pan = xcd * 8 + (seq >> 3);   // 0..63 row panel
  const int xcol = seq & 7;
  __shared__ u16 As[128 * 32];
  __shared__ u16 Bs[128 * 32];
  const int tid = threadIdx.x;
  const int w = tid >> 6;
  const int lane = tid & 63;
  const int lo = lane & 15, hi = lane >> 4;
  const int brow = pan * 128;
  const int bcol = xcol * 128;
  const int wr = (w >> 1) * 64;
  const int wc = (w & 1) * 64;

  f32x4 acc[4][4] = {};

  for (int k0 = 0; k0 < K; k0 += 32) {
    __syncthreads();
    #pragma unroll
    for (int i = 0; i < 2; i++) {
      int g = i * 256 + tid;
      int row = g >> 2;
      int lc = (g & 3) ^ ((row >> 1) & 3);
      gload_lds16(A + (size_t)(brow + row) * K + k0 + lc * 8,
                  (void*)(As + (size_t)g * 8));
      gload_lds16(Bt + (size_t)(bcol + row) * K + k0 + lc * 8,
                  (void*)(Bs + (size_t)g * 8));
    }
    __syncthreads();
    __builtin_amdgcn_s_setprio(1);
    bf16x8 af[4], bfr[4];
    #pragma unroll
    for (int mi = 0; mi < 4; mi++) {
      int row = wr + mi * 16 + lo;
      int ch = hi ^ ((row >> 1) & 3);
      af[mi] = *(const bf16x8*)(As + row * 32 + ch * 8);
    }
    #pragma unroll
    for (int ni = 0; ni < 4; ni++) {
      int row = wc + ni * 16 + lo;
      int ch = hi ^ ((row >> 1) & 3);
      bfr[ni] = *(const bf16x8*)(Bs + row * 32 + ch * 8);
    }
    #pragma unroll
    for (int mi = 0; mi < 4; mi++)
      #pragma unroll
      for (int ni = 0; ni < 4; ni++)
        acc[mi][ni] = __builtin_amdgcn_mfma_f32_16x16x32_bf16(
            af[mi], bfr[ni], acc[mi][ni], 0, 0, 0);
    __builtin_amdgcn_s_setprio(0);
  }

  #pragma unroll
  for (int mi = 0; mi < 4; mi++)
    #pragma unroll
    for (int ni = 0; ni < 4; ni++) {
      int row = brow + wr + mi * 16 + hi * 4;
      int col = bcol + wc + ni * 16 + lo;
      float bv = bias[col];
      #pragma unroll
      for (int r = 0; r < 4; r++)
        C[(size_t)(row + r) * N + col] = acc[mi][ni][r] + bv;
    }
}

// ---------------- flash attention (r17-proven: per-sb interleave) ----------
__global__ __launch_bounds__(256) void attn_kernel(
    const u16* __restrict__ Qp, const u16* __restrict__ Kp,
    const u16* __restrict__ Vp, u16* __restrict__ O)
{
  constexpr int Bb = 4, E = 1024, Nn = 2048;
  constexpr int NT = Nn / 64;
  __shared__ u16 Ks[2][64 * 64];    // K tile [n][d], swizzled
  __shared__ u16 Vt[2][64 * 64];    // V^T tile [d][n], swizzled

  const int tid = threadIdx.x;
  const int lane = tid & 63;
  const int w = tid >> 6;
  const int l31 = lane & 31;        // this lane's q-row (col of S^T)
  const int hi5 = lane >> 5;        // 0/1: half selector

  // XCD-grouping swizzle: blocks sharing (b,h) -> same XCD L2
  const int wg = blockIdx.x;
  const int swz = (wg & 7) * 128 + (wg >> 3);
  const int b_ = swz >> 8;
  const int h = (swz >> 4) & 15;
  const int mbase = (swz & 15) * 128 + w * 32;
  const int m = mbase + l31;

  // Q B-frags (pre-scaled by 1/sqrt(d)*log2e)
  bf16x8 q[4];
  {
    const u16* qrow = Qp + (size_t)(m * Bb + b_) * E + h * 64;
    #pragma unroll
    for (int kb = 0; kb < 4; kb++)
      q[kb] = *(const bf16x8*)(qrow + kb * 16 + hi5 * 8);
  }

  f32x16 oacc[2] = {};              // O^T: col=m, row=d (2 d-subtiles)
  float lrun = 0.f;                 // per-lane PARTIAL (own 32 n of row m)

  // staging assignments + strength-reduced pointers
  const int nrK = tid >> 3;            // + i*32
  const int q8K = (tid & 7) * 8;
  const int dq = (tid & 15) * 4;       // V: 4x4 block at (nq.., dq..)
  const int nq = (tid >> 4) * 4;
  const size_t rstride = (size_t)Bb * E;          // one n-row
  const size_t KSTEP = 64 * rstride;              // one KV tile
  const u16* kpt = Kp + (size_t)nrK * rstride + (size_t)b_ * E + h * 64 + q8K;
  const u16* vpt = Vp + (size_t)nq * rstride + (size_t)b_ * E + h * 64 + dq;

  // prefetch tile 0
  u16x8 kreg[2];
  u16x4 vreg[4];
  kreg[0] = *(const u16x8*)(kpt);
  kreg[1] = *(const u16x8*)(kpt + 32 * rstride);
  #pragma unroll
  for (int j = 0; j < 4; j++)
    vreg[j] = *(const u16x4*)(vpt + j * rstride);
  kpt += KSTEP; vpt += KSTEP;

  int it = 0;
  for (int t = 0; t < NT; t++, it ^= 1) {
    // stage regs -> LDS buf[it]
    #pragma unroll
    for (int i = 0; i < 2; i++)
      *(u16x8*)(&Ks[it][swz_off(i * 32 + nrK, q8K)]) = kreg[i];
    #pragma unroll
    for (int jw = 0; jw < 4; jw++) {
      u16x4 colv;
      #pragma unroll
      for (int j = 0; j < 4; j++) colv[j] = vreg[j][jw];
      *(u16x4*)(&Vt[it][swz_off(dq + jw, nq)]) = colv;
    }
    __syncthreads();
    // issue next tile's global loads; they retire under compute
    if (t < NT - 1) {
      kreg[0] = *(const u16x8*)(kpt);
      kreg[1] = *(const u16x8*)(kpt + 32 * rstride);
      #pragma unroll
      for (int j = 0; j < 4; j++)
        vreg[j] = *(const u16x4*)(vpt + j * rstride);
      kpt += KSTEP; vpt += KSTEP;
    }
    const u16* ksp = &Ks[it][0];
    const u16* vtp = &Vt[it][0];

    // S^T = K Q^T (log2 domain), 32x32x16
    f32x16 st[2];
    __builtin_amdgcn_s_setprio(1);
    #pragma unroll
    for (int sb = 0; sb < 2; sb++) {
      f32x16 tacc = {};
      #pragma unroll
      for (int kb = 0; kb < 4; kb++) {
        bf16x8 kf = *(const bf16x8*)(ksp + swz_off(sb * 32 + l31, kb * 16 + hi5 * 8));
        tacc = __builtin_amdgcn_mfma_f32_32x32x16_bf16(kf, q[kb], tacc, 0, 0, 0);
      }
      st[sb] = tacc;
    }
    __builtin_amdgcn_s_setprio(0);

    // per-sb: exp2/pack(sb) -> pb(sb) -> PV(sb) ; exp2(sb1) overlaps PV(sb0)
    #pragma unroll
    for (int sb = 0; sb < 2; sb++) {
      u32 pks[8];
      float ra = 0.f, rb = 0.f, rc = 0.f, rd = 0.f;
      #pragma unroll
      for (int j = 0; j < 8; j++) {
        float p0 = fast_exp2(st[sb][2 * j]);
        float p1 = fast_exp2(st[sb][2 * j + 1]);
        if (j & 1) { ra += p0; rb += p1; } else { rc += p0; rd += p1; }
        pks[j] = cvtpk_bf16(p0, p1);
      }
      lrun += (ra + rb) + (rc + rd);

      bf16x8 pb[2];
      #pragma unroll
      for (int c = 0; c < 2; c++) {
        u32 a0 = pks[4 * c + 0], b0 = pks[4 * c + 2];
        u32 a1 = pks[4 * c + 1], b1 = pks[4 * c + 3];
        permswap32(a0, b0);
        permswap32(a1, b1);
        union { u32 d[4]; bf16x8 v; } u;
        u.d[0] = a0; u.d[1] = a1; u.d[2] = b0; u.d[3] = b1;
        pb[c] = u.v;
      }

      __builtin_amdgcn_s_setprio(1);
      #pragma unroll
      for (int dsb = 0; dsb < 2; dsb++) {
        #pragma unroll
        for (int c = 0; c < 2; c++) {
          int kb = sb * 2 + c;
          bf16x8 vf = *(const bf16x8*)(vtp + swz_off(dsb * 32 + l31, kb * 16 + hi5 * 8));
          oacc[dsb] = __builtin_amdgcn_mfma_f32_32x32x16_bf16(vf, pb[c], oacc[dsb], 0, 0, 0);
        }
      }
      __builtin_amdgcn_s_setprio(0);
    }
  }

  // epilogue: combine lrun across the lane pair (once), divide, store
  float l = lrun + __shfl_xor(lrun, 32);
  float inv = 1.f / l;
  u16* orow = O + (size_t)(m * Bb + b_) * E + h * 64;
  #pragma unroll
  for (int dsb = 0; dsb < 2; dsb++) {
    #pragma unroll
    for (int qd = 0; qd < 4; qd++) {
      u16x4 o;
      #pragma unroll
      for (int t = 0; t < 4; t++) o[t] = f2bf(oacc[dsb][qd * 4 + t] * inv);
      *(u16x4*)(orow + dsb * 32 + qd * 8 + hi5 * 4) = o;
    }
  }
}

extern "C" void kernel_launch(void* const* d_in, const int* in_sizes, int n_in,
                              void* d_out, int out_size, void* d_ws, size_t ws_size,
                              hipStream_t stream) {
  const float* query = (const float*)d_in[0];
  const float* key   = (const float*)d_in[1];
  const float* value = (const float*)d_in[2];
  const float* Wq = (const float*)d_in[3];
  const float* bq = (const float*)d_in[4];
  const float* Wk = (const float*)d_in[5];
  const float* bk = (const float*)d_in[6];
  const float* Wv = (const float*)d_in[7];
  const float* bv = (const float*)d_in[8];
  const float* Wo = (const float*)d_in[9];
  const float* bo = (const float*)d_in[10];
  float* out = (float*)d_out;

  const float QSCALE = 0.125f * LOG2E;  // 1/sqrt(64) * log2(e)

  const size_t XE = (size_t)2048 * 4 * 1024;  // M*B*E
  const size_t WE = (size_t)1024 * 1024;
  u16* ws  = (u16*)d_ws;
  u16* Qp  = ws;
  u16* Kp  = Qp + XE;
  u16* Vp  = Kp + XE;
  u16* Ob  = Vp + XE;       // attention output (bf16)
  u16* Wqt = Ob + XE;
  u16* Wkt = Wqt + WE;
  u16* Wvt = Wkt + WE;
  u16* Wot = Wvt + WE;

  dim3 blk(256);
  transpose_cvt4<<<dim3(32, 32, 4), blk, 0, stream>>>(
      Wq, Wk, Wv, Wo, Wqt, Wkt, Wvt, Wot);

  proj_qkv<<<1536, blk, 0, stream>>>(
      query, key, value, Wqt, Wkt, Wvt, bq, bk, bv, Qp, Kp, Vp, QSCALE);

  attn_kernel<<<1024, blk, 0, stream>>>(Qp, Kp, Vp, Ob);

  gemm_out<<<512, blk, 0, stream>>>(Ob, Wot, bo, out);
}

// Round 22
// 198.801 us; speedup vs baseline: 1.0222x; 1.0019x over previous
//
#include <hip/hip_runtime.h>

typedef unsigned short u16;
typedef unsigned int u32;
typedef __bf16 bf16x8 __attribute__((ext_vector_type(8)));
typedef float f32x4 __attribute__((ext_vector_type(4)));
typedef float f32x16 __attribute__((ext_vector_type(16)));
typedef unsigned short u16x8 __attribute__((ext_vector_type(8)));
typedef unsigned short u16x4 __attribute__((ext_vector_type(4)));

#define LOG2E 1.44269504088896f

__device__ __forceinline__ float fast_exp2(float x) {
#if __has_builtin(__builtin_amdgcn_exp2f)
  return __builtin_amdgcn_exp2f(x);
#else
  return exp2f(x);
#endif
}

// HW bf16 convert (compiler emits v_cvt_pk_bf16_f32 pairs)
__device__ __forceinline__ u16 f2bf(float x) {
  union { __bf16 b; u16 u; } c;
  c.b = (__bf16)x;
  return c.u;
}

// packed f32x2 -> bf16x2 in one instruction (no builtin on gfx950; T12)
__device__ __forceinline__ u32 cvtpk_bf16(float lo_, float hi_) {
  u32 r;
  asm("v_cvt_pk_bf16_f32 %0, %1, %2" : "=v"(r) : "v"(lo_), "v"(hi_));
  return r;
}

// v_permlane32_swap_b32: a[l>=32] <-> b[l<32].
__device__ __forceinline__ void permswap32(u32& a, u32& b) {
  asm volatile("v_permlane32_swap_b32 %0, %1" : "+v"(a), "+v"(b));
}

__device__ __forceinline__ void gload_lds16(const void* g, void* l) {
  __builtin_amdgcn_global_load_lds(
      (__attribute__((address_space(1))) void*)(g),
      (__attribute__((address_space(3))) void*)(l), 16, 0, 0);
}

// XOR bank swizzle for [rows][64 u16] LDS tiles, 16B-chunk granularity
// (attn tiles, row stride 128B).
__device__ __forceinline__ int swz_off(int row, int col) {
  return row * 64 + ((((col >> 3) ^ (row ^ (row >> 3))) & 7) << 3) + (col & 7);
}

// ---------------- all 4 weights: W (K x N) -> W^T (N x K) bf16, one dispatch --
__global__ __launch_bounds__(256) void transpose_cvt4(
    const float* __restrict__ Wq, const float* __restrict__ Wk,
    const float* __restrict__ Wv, const float* __restrict__ Wo,
    u16* __restrict__ Wqt, u16* __restrict__ Wkt,
    u16* __restrict__ Wvt, u16* __restrict__ Wot) {
  const int E = 1024;
  const float* W = blockIdx.z == 0 ? Wq : blockIdx.z == 1 ? Wk
                   : blockIdx.z == 2 ? Wv : Wo;
  u16* Wt = blockIdx.z == 0 ? Wqt : blockIdx.z == 1 ? Wkt
            : blockIdx.z == 2 ? Wvt : Wot;
  __shared__ float tile[32][33];
  int tx = threadIdx.x & 31, ty = threadIdx.x >> 5;  // 32 x 8
  int bx = blockIdx.x * 32, by = blockIdx.y * 32;
  #pragma unroll
  for (int i = 0; i < 32; i += 8)
    tile[ty + i][tx] = W[(size_t)(by + ty + i) * E + bx + tx];
  __syncthreads();
  #pragma unroll
  for (int i = 0; i < 32; i += 8)
    Wt[(size_t)(bx + ty + i) * E + by + tx] = f2bf(tile[tx][ty + i]);
}

// ---------------- fused Q/K/V projection, BK=32, panel-grouped XCD swizzle --
// Session-best variant: fully-async staging, single-buffered 24 KB LDS,
// A staged raw fp32 (pre-swizzled source), cvt at fragment-read time.
__global__ __launch_bounds__(256) void proj_qkv(
    const float* __restrict__ Xq, const float* __restrict__ Xk,
    const float* __restrict__ Xv,
    const u16* __restrict__ Wqt, const u16* __restrict__ Wkt,
    const u16* __restrict__ Wvt,
    const float* __restrict__ bq, const float* __restrict__ bk,
    const float* __restrict__ bv,
    u16* __restrict__ Qp, u16* __restrict__ Kp, u16* __restrict__ Vp,
    float qscale)
{
  constexpr int K = 1024, N = 1024;
  // bid <-> (xcd, seq) <-> (panel, col): bijective
  const int bid = blockIdx.x;          // 0..1535
  const int xcd = bid & 7;
  const int seq = bid >> 3;            // 0..191
  const int pan = xcd * 24 + (seq >> 3);  // 0..191 (z,y panel)
  const int xcol = seq & 7;            // col tile
  const int z = pan / 64;
  const int y = pan % 64;

  const float* A; const u16* Bt; const float* bias; u16* C; float oscale;
  if (z == 0)      { A = Xq; Bt = Wqt; bias = bq; C = Qp; oscale = qscale; }
  else if (z == 1) { A = Xk; Bt = Wkt; bias = bk; C = Kp; oscale = 1.f; }
  else             { A = Xv; Bt = Wvt; bias = bv; C = Vp; oscale = 1.f; }

  __shared__ float As32[128 * 32];   // fp32 A tile, 8 16B-chunks/row, XOR swz
  __shared__ u16 Bs[128 * 32];       // bf16 B tile, 4 16B-chunks/row, XOR swz
  const int tid = threadIdx.x;
  const int w = tid >> 6;
  const int lane = tid & 63;
  const int lo = lane & 15, hi = lane >> 4;
  const int brow = y * 128;
  const int bcol = xcol * 128;
  const int wr = (w >> 1) * 64;
  const int wc = (w & 1) * 64;

  f32x4 acc[4][4] = {};

  for (int k0 = 0; k0 < K; k0 += 32) {
    __syncthreads();
    // B(t): 2 gload_lds (linear dest; source chunk pre-swizzled)
    #pragma unroll
    for (int i = 0; i < 2; i++) {
      int g = i * 256 + tid;
      int row = g >> 2;
      int lc = (g & 3) ^ ((row >> 1) & 3);
      gload_lds16(Bt + (size_t)(bcol + row) * K + k0 + lc * 8,
                  (void*)(Bs + (size_t)g * 8));
    }
    // A(t): 4 gload_lds fp32 (linear dest; source pre-swizzled)
    #pragma unroll
    for (int i = 0; i < 4; i++) {
      int g = i * 256 + tid;
      int row = g >> 3;
      int lc = (g & 7) ^ (row & 7);
      gload_lds16(A + (size_t)(brow + row) * K + k0 + lc * 4,
                  (void*)(As32 + (size_t)g * 4));
    }
    __syncthreads();   // drains all gloads

    __builtin_amdgcn_s_setprio(1);
    bf16x8 af[4], bfr[4];
    #pragma unroll
    for (int mi = 0; mi < 4; mi++) {
      int row = wr + mi * 16 + lo;
      int s_ = row & 7;
      int c0 = hi * 2;
      f32x4 fa = *(const f32x4*)(As32 + row * 32 + ((c0 ^ s_) << 2));
      f32x4 fb = *(const f32x4*)(As32 + row * 32 + (((c0 + 1) ^ s_) << 2));
      union { u32 d[4]; bf16x8 v; } ua;
      ua.d[0] = cvtpk_bf16(fa[0], fa[1]);
      ua.d[1] = cvtpk_bf16(fa[2], fa[3]);
      ua.d[2] = cvtpk_bf16(fb[0], fb[1]);
      ua.d[3] = cvtpk_bf16(fb[2], fb[3]);
      af[mi] = ua.v;
    }
    #pragma unroll
    for (int ni = 0; ni < 4; ni++) {
      int row = wc + ni * 16 + lo;
      int ch = hi ^ ((row >> 1) & 3);
      bfr[ni] = *(const bf16x8*)(Bs + row * 32 + ch * 8);
    }
    #pragma unroll
    for (int mi = 0; mi < 4; mi++)
      #pragma unroll
      for (int ni = 0; ni < 4; ni++)
        acc[mi][ni] = __builtin_amdgcn_mfma_f32_16x16x32_bf16(
            af[mi], bfr[ni], acc[mi][ni], 0, 0, 0);
    __builtin_amdgcn_s_setprio(0);
  }

  #pragma unroll
  for (int mi = 0; mi < 4; mi++)
    #pragma unroll
    for (int ni = 0; ni < 4; ni++) {
      int row = brow + wr + mi * 16 + hi * 4;
      int col = bcol + wc + ni * 16 + lo;
      float bv = bias[col];
      #pragma unroll
      for (int r = 0; r < 4; r++) {
        float v = (acc[mi][ni][r] + bv) * oscale;
        C[(size_t)(row + r) * N + col] = f2bf(v);
      }
    }
}

// ---------------- output projection, BK=32, panel-grouped XCD swizzle -------
__global__ __launch_bounds__(256) void gemm_out(
    const u16* __restrict__ A, const u16* __restrict__ Bt,
    const float* __restrict__ bias, float* __restrict__ C)
{
  constexpr int K = 1024, N = 1024;
  const int bid = blockIdx.x;          // 0..511
  const int xcd = bid & 7;
  const int seq = bid >> 3;            // 0..63
  const int pan = xcd * 8 + (seq >> 3);   // 0..63 row panel
  const int xcol = seq & 7;
  __shared__ u16 As[128 * 32];
  __shared__ u16 Bs[128 * 32];
  const int tid = threadIdx.x;
  const int w = tid >> 6;
  const int lane = tid & 63;
  const int lo = lane & 15, hi = lane >> 4;
  const int brow = pan * 128;
  const int bcol = xcol * 128;
  const int wr = (w >> 1) * 64;
  const int wc = (w & 1) * 64;

  f32x4 acc[4][4] = {};

  for (int k0 = 0; k0 < K; k0 += 32) {
    __syncthreads();
    #pragma unroll
    for (int i = 0; i < 2; i++) {
      int g = i * 256 + tid;
      int row = g >> 2;
      int lc = (g & 3) ^ ((row >> 1) & 3);
      gload_lds16(A + (size_t)(brow + row) * K + k0 + lc * 8,
                  (void*)(As + (size_t)g * 8));
      gload_lds16(Bt + (size_t)(bcol + row) * K + k0 + lc * 8,
                  (void*)(Bs + (size_t)g * 8));
    }
    __syncthreads();
    __builtin_amdgcn_s_setprio(1);
    bf16x8 af[4], bfr[4];
    #pragma unroll
    for (int mi = 0; mi < 4; mi++) {
      int row = wr + mi * 16 + lo;
      int ch = hi ^ ((row >> 1) & 3);
      af[mi] = *(const bf16x8*)(As + row * 32 + ch * 8);
    }
    #pragma unroll
    for (int ni = 0; ni < 4; ni++) {
      int row = wc + ni * 16 + lo;
      int ch = hi ^ ((row >> 1) & 3);
      bfr[ni] = *(const bf16x8*)(Bs + row * 32 + ch * 8);
    }
    #pragma unroll
    for (int mi = 0; mi < 4; mi++)
      #pragma unroll
      for (int ni = 0; ni < 4; ni++)
        acc[mi][ni] = __builtin_amdgcn_mfma_f32_16x16x32_bf16(
            af[mi], bfr[ni], acc[mi][ni], 0, 0, 0);
    __builtin_amdgcn_s_setprio(0);
  }

  #pragma unroll
  for (int mi = 0; mi < 4; mi++)
    #pragma unroll
    for (int ni = 0; ni < 4; ni++) {
      int row = brow + wr + mi * 16 + hi * 4;
      int col = bcol + wc + ni * 16 + lo;
      float bv = bias[col];
      #pragma unroll
      for (int r = 0; r < 4; r++)
        C[(size_t)(row + r) * N + col] = acc[mi][ni][r] + bv;
    }
}

// ---------------- flash attention (per-sb interleaved softmax/PV) ----------
__global__ __launch_bounds__(256) void attn_kernel(
    const u16* __restrict__ Qp, const u16* __restrict__ Kp,
    const u16* __restrict__ Vp, u16* __restrict__ O)
{
  constexpr int Bb = 4, E = 1024, Nn = 2048;
  constexpr int NT = Nn / 64;
  __shared__ u16 Ks[2][64 * 64];    // K tile [n][d], swizzled
  __shared__ u16 Vt[2][64 * 64];    // V^T tile [d][n], swizzled

  const int tid = threadIdx.x;
  const int lane = tid & 63;
  const int w = tid >> 6;
  const int l31 = lane & 31;        // this lane's q-row (col of S^T)
  const int hi5 = lane >> 5;        // 0/1: half selector

  // XCD-grouping swizzle: blocks sharing (b,h) -> same XCD L2
  const int wg = blockIdx.x;
  const int swz = (wg & 7) * 128 + (wg >> 3);
  const int b_ = swz >> 8;
  const int h = (swz >> 4) & 15;
  const int mbase = (swz & 15) * 128 + w * 32;
  const int m = mbase + l31;

  // Q B-frags (pre-scaled by 1/sqrt(d)*log2e)
  bf16x8 q[4];
  {
    const u16* qrow = Qp + (size_t)(m * Bb + b_) * E + h * 64;
    #pragma unroll
    for (int kb = 0; kb < 4; kb++)
      q[kb] = *(const bf16x8*)(qrow + kb * 16 + hi5 * 8);
  }

  f32x16 oacc[2] = {};              // O^T: col=m, row=d (2 d-subtiles)
  float lrun = 0.f;                 // per-lane PARTIAL (own 32 n of row m)

  // staging assignments + strength-reduced pointers
  const int nrK = tid >> 3;            // + i*32
  const int q8K = (tid & 7) * 8;
  const int dq = (tid & 15) * 4;       // V: 4x4 block at (nq.., dq..)
  const int nq = (tid >> 4) * 4;
  const size_t rstride = (size_t)Bb * E;          // one n-row
  const size_t KSTEP = 64 * rstride;              // one KV tile
  const u16* kpt = Kp + (size_t)nrK * rstride + (size_t)b_ * E + h * 64 + q8K;
  const u16* vpt = Vp + (size_t)nq * rstride + (size_t)b_ * E + h * 64 + dq;

  // prefetch tile 0
  u16x8 kreg[2];
  u16x4 vreg[4];
  kreg[0] = *(const u16x8*)(kpt);
  kreg[1] = *(const u16x8*)(kpt + 32 * rstride);
  #pragma unroll
  for (int j = 0; j < 4; j++)
    vreg[j] = *(const u16x4*)(vpt + j * rstride);
  kpt += KSTEP; vpt += KSTEP;

  int it = 0;
  for (int t = 0; t < NT; t++, it ^= 1) {
    // stage regs -> LDS buf[it]
    #pragma unroll
    for (int i = 0; i < 2; i++)
      *(u16x8*)(&Ks[it][swz_off(i * 32 + nrK, q8K)]) = kreg[i];
    #pragma unroll
    for (int jw = 0; jw < 4; jw++) {
      u16x4 colv;
      #pragma unroll
      for (int j = 0; j < 4; j++) colv[j] = vreg[j][jw];
      *(u16x4*)(&Vt[it][swz_off(dq + jw, nq)]) = colv;
    }
    __syncthreads();
    // issue next tile's global loads; they retire under compute
    if (t < NT - 1) {
      kreg[0] = *(const u16x8*)(kpt);
      kreg[1] = *(const u16x8*)(kpt + 32 * rstride);
      #pragma unroll
      for (int j = 0; j < 4; j++)
        vreg[j] = *(const u16x4*)(vpt + j * rstride);
      kpt += KSTEP; vpt += KSTEP;
    }
    const u16* ksp = &Ks[it][0];
    const u16* vtp = &Vt[it][0];

    // S^T = K Q^T (log2 domain), 32x32x16
    f32x16 st[2];
    __builtin_amdgcn_s_setprio(1);
    #pragma unroll
    for (int sb = 0; sb < 2; sb++) {
      f32x16 tacc = {};
      #pragma unroll
      for (int kb = 0; kb < 4; kb++) {
        bf16x8 kf = *(const bf16x8*)(ksp + swz_off(sb * 32 + l31, kb * 16 + hi5 * 8));
        tacc = __builtin_amdgcn_mfma_f32_32x32x16_bf16(kf, q[kb], tacc, 0, 0, 0);
      }
      st[sb] = tacc;
    }
    __builtin_amdgcn_s_setprio(0);

    // per-sb: exp2/pack(sb) -> pb(sb) -> PV(sb) ; exp2(sb1) overlaps PV(sb0)
    #pragma unroll
    for (int sb = 0; sb < 2; sb++) {
      u32 pks[8];
      float ra = 0.f, rb = 0.f, rc = 0.f, rd = 0.f;
      #pragma unroll
      for (int j = 0; j < 8; j++) {
        float p0 = fast_exp2(st[sb][2 * j]);
        float p1 = fast_exp2(st[sb][2 * j + 1]);
        if (j & 1) { ra += p0; rb += p1; } else { rc += p0; rd += p1; }
        pks[j] = cvtpk_bf16(p0, p1);
      }
      lrun += (ra + rb) + (rc + rd);

      bf16x8 pb[2];
      #pragma unroll
      for (int c = 0; c < 2; c++) {
        u32 a0 = pks[4 * c + 0], b0 = pks[4 * c + 2];
        u32 a1 = pks[4 * c + 1], b1 = pks[4 * c + 3];
        permswap32(a0, b0);
        permswap32(a1, b1);
        union { u32 d[4]; bf16x8 v; } u;
        u.d[0] = a0; u.d[1] = a1; u.d[2] = b0; u.d[3] = b1;
        pb[c] = u.v;
      }

      __builtin_amdgcn_s_setprio(1);
      #pragma unroll
      for (int dsb = 0; dsb < 2; dsb++) {
        #pragma unroll
        for (int c = 0; c < 2; c++) {
          int kb = sb * 2 + c;
          bf16x8 vf = *(const bf16x8*)(vtp + swz_off(dsb * 32 + l31, kb * 16 + hi5 * 8));
          oacc[dsb] = __builtin_amdgcn_mfma_f32_32x32x16_bf16(vf, pb[c], oacc[dsb], 0, 0, 0);
        }
      }
      __builtin_amdgcn_s_setprio(0);
    }
  }

  // epilogue: combine lrun across the lane pair (once), divide, store
  float l = lrun + __shfl_xor(lrun, 32);
  float inv = 1.f / l;
  u16* orow = O + (size_t)(m * Bb + b_) * E + h * 64;
  #pragma unroll
  for (int dsb = 0; dsb < 2; dsb++) {
    #pragma unroll
    for (int qd = 0; qd < 4; qd++) {
      u16x4 o;
      #pragma unroll
      for (int t = 0; t < 4; t++) o[t] = f2bf(oacc[dsb][qd * 4 + t] * inv);
      *(u16x4*)(orow + dsb * 32 + qd * 8 + hi5 * 4) = o;
    }
  }
}

extern "C" void kernel_launch(void* const* d_in, const int* in_sizes, int n_in,
                              void* d_out, int out_size, void* d_ws, size_t ws_size,
                              hipStream_t stream) {
  const float* query = (const float*)d_in[0];
  const float* key   = (const float*)d_in[1];
  const float* value = (const float*)d_in[2];
  const float* Wq = (const float*)d_in[3];
  const float* bq = (const float*)d_in[4];
  const float* Wk = (const float*)d_in[5];
  const float* bk = (const float*)d_in[6];
  const float* Wv = (const float*)d_in[7];
  const float* bv = (const float*)d_in[8];
  const float* Wo = (const float*)d_in[9];
  const float* bo = (const float*)d_in[10];
  float* out = (float*)d_out;

  const float QSCALE = 0.125f * LOG2E;  // 1/sqrt(64) * log2(e)

  const size_t XE = (size_t)2048 * 4 * 1024;  // M*B*E
  const size_t WE = (size_t)1024 * 1024;
  u16* ws  = (u16*)d_ws;
  u16* Qp  = ws;
  u16* Kp  = Qp + XE;
  u16* Vp  = Kp + XE;
  u16* Ob  = Vp + XE;       // attention output (bf16)
  u16* Wqt = Ob + XE;
  u16* Wkt = Wqt + WE;
  u16* Wvt = Wkt + WE;
  u16* Wot = Wvt + WE;

  dim3 blk(256);
  transpose_cvt4<<<dim3(32, 32, 4), blk, 0, stream>>>(
      Wq, Wk, Wv, Wo, Wqt, Wkt, Wvt, Wot);

  proj_qkv<<<1536, blk, 0, stream>>>(
      query, key, value, Wqt, Wkt, Wvt, bq, bk, bv, Qp, Kp, Vp, QSCALE);

  attn_kernel<<<1024, blk, 0, stream>>>(Qp, Kp, Vp, Ob);

  gemm_out<<<512, blk, 0, stream>>>(Ob, Wot, bo, out);
}